// Round 17
// baseline (155.026 us; speedup 1.0000x reference)
//
#include <hip/hip_runtime.h>

// Problem constants
#define BB 32
#define SS 512
#define DD 768
#define HH 12
#define HDIM 64
#define OL 256        // pooled query length
#define NQKV 2304     // 3*DD
#define GM (BB*SS)    // 16384 rows into the QKV GEMM

#define NEG2 (-14426.9504089f)   // -10000 * log2(e)

typedef __bf16 bf16_t;
typedef bf16_t bf16x8 __attribute__((ext_vector_type(8)));
typedef float f32x4 __attribute__((ext_vector_type(4)));
typedef unsigned short u16x8 __attribute__((ext_vector_type(8)));

__device__ __forceinline__ unsigned short f2bf(float f) {
  unsigned u = __float_as_uint(f);
  u = u + 0x7FFFu + ((u >> 16) & 1u);   // RNE
  return (unsigned short)(u >> 16);
}
__device__ __forceinline__ float b2f(unsigned short s) {
  return __uint_as_float(((unsigned)s) << 16);
}

// ---------------------------------------------------------------- fused prep
// blocks [0,1728): W f32->bf16
// blocks [1728,1792): mask -> kbias/invn/nmask/out_nm
// blocks [1792,7936): hidden -> Abf (bf16) + Apool (mask-weighted pooled bf16)
__global__ __launch_bounds__(256) void prep_all(
    const float* __restrict__ hidden,
    const void* __restrict__ mraw,
    const float* __restrict__ W,
    unsigned short* __restrict__ Btb,
    unsigned short* __restrict__ Abf,
    unsigned short* __restrict__ Apool,
    float* __restrict__ kbias,
    float* __restrict__ invn,
    unsigned char* __restrict__ nmask,
    float* __restrict__ out_nm) {
  const int blk = blockIdx.x;
  const int t = threadIdx.x;
  const unsigned char* mb = (const unsigned char*)mraw;

  if (blk < 1728) {
    // ---- W conversion (442368 float4 items)
    const int i = blk * 256 + t;
    float4 v = ((const float4*)W)[i];
    ushort4 o;
    o.x = f2bf(v.x); o.y = f2bf(v.y); o.z = f2bf(v.z); o.w = f2bf(v.w);
    ((ushort4*)Btb)[i] = o;
  } else if (blk < 1792) {
    // ---- mask prep (16384 positions)
    const int idx = (blk - 1728) * 256 + t;
    const int b = idx >> 9, s = idx & 511;
    const bool isbyte = (mb[1] != 0);
    const int mv = isbyte ? (int)(mb[idx] != 0) : (int)(((const int*)mraw)[idx] != 0);
    kbias[idx] = mv ? 0.f : NEG2;
    if (s < OL) {
      const int i0 = b * SS + 2 * s, i1 = i0 + 1;
      const int m0 = isbyte ? (int)(mb[i0] != 0) : (int)(((const int*)mraw)[i0] != 0);
      const int m1 = isbyte ? (int)(mb[i1] != 0) : (int)(((const int*)mraw)[i1] != 0);
      const int n = m0 + m1;
      invn[b * OL + s] = (n > 0) ? 1.f / (float)n : 1.f;
      nmask[b * OL + s] = (n > 0) ? 1 : 0;
      out_nm[b * OL + s] = (n > 0) ? 1.f : 0.f;
    }
  } else {
    // ---- hidden conversion + pooling (1572864 items; reads mask directly)
    const int i = (blk - 1792) * 256 + t;
    const int c = (i % 192) * 4;
    const int ol = i / 192;
    const int b = ol >> 8, o = ol & 255;
    const int s0 = b * SS + 2 * o;
    const bool isbyte = (mb[1] != 0);
    const int m0 = isbyte ? (int)(mb[s0] != 0) : (int)(((const int*)mraw)[s0] != 0);
    const int m1 = isbyte ? (int)(mb[s0 + 1] != 0) : (int)(((const int*)mraw)[s0 + 1] != 0);
    const int n = m0 + m1;
    const float inv = (n > 0) ? 1.f / (float)n : 1.f;
    const float m0v = (float)m0, m1v = (float)m1;
    const float4 h0 = *(const float4*)(hidden + (size_t)s0 * DD + c);
    const float4 h1 = *(const float4*)(hidden + (size_t)(s0 + 1) * DD + c);
    ushort4 a0, a1, ap;
    a0.x = f2bf(h0.x); a0.y = f2bf(h0.y); a0.z = f2bf(h0.z); a0.w = f2bf(h0.w);
    a1.x = f2bf(h1.x); a1.y = f2bf(h1.y); a1.z = f2bf(h1.z); a1.w = f2bf(h1.w);
    ap.x = f2bf((h0.x * m0v + h1.x * m1v) * inv);
    ap.y = f2bf((h0.y * m0v + h1.y * m1v) * inv);
    ap.z = f2bf((h0.z * m0v + h1.z * m1v) * inv);
    ap.w = f2bf((h0.w * m0v + h1.w * m1v) * inv);
    *(ushort4*)(Abf + (size_t)s0 * DD + c) = a0;
    *(ushort4*)(Abf + (size_t)(s0 + 1) * DD + c) = a1;
    *(ushort4*)(Apool + (size_t)ol * DD + c) = ap;
  }
}

// ---------------------------------------------------------------- QKV GEMM
// R13 structure with B moved OFF LDS into registers (reg-staged weights):
// 128x128 tile, BK=64, 4 waves (2M x 2N); A via global_load_lds dbuf
// (2 x 16 KiB), B frags loaded straight from L2 into VGPRs, double-buffered
// across a fully-unrolled K-loop (static indexing). LDS traffic per block
// per K-tile: 96 KB -> 48 KB. Mixed vmcnt ledger: per tile A-DMA 4 + B-reg
// 8 = 12 ops/thread; steady wait vmcnt(12) retires exactly A(kt)+B(kt).
// Grid 1920 = 8 XCDs x 240: l<1536 -> K/V (M=16384); l>=1536 -> Q (Apool).
#define NT 12   // 768 / 64
__global__ __launch_bounds__(256, 2) void gemm_qkv(
    const unsigned short* __restrict__ A,      // [16384][768]
    const unsigned short* __restrict__ Apool,  // [8192][768]
    const unsigned short* __restrict__ Bt,     // [2304][768]
    const float* __restrict__ bias,
    unsigned short* __restrict__ Kbuf,   // [B*S][768]
    unsigned short* __restrict__ qp,     // [B*OL][768]
    unsigned short* __restrict__ vT,     // [B][H][64][512]
    const unsigned char* __restrict__ nmask) {
  __shared__ __align__(16) char smem[34816];  // A dbuf 32K; V-epi tile 34816

  const int t = threadIdx.x;
  const int lane = t & 63;
  const int w = t >> 6;          // 0..3
  const int wm = w >> 1, wn = w & 1;
  const int fr = lane & 15, hi = lane >> 4;

  const int p = blockIdx.x;
  const int l = (p & 7) * 240 + (p >> 3);
  const bool isQ = l >= 1536;
  int m0, n0;
  if (!isQ) { m0 = (l / 12) * 128; n0 = 768 + (l % 12) * 128; }
  else      { const int l2 = l - 1536; m0 = (l2 / 6) * 128; n0 = (l2 % 6) * 128; }
  const unsigned short* Asel = isQ ? Apool : A;

  f32x4 acc[4][4] = {};

  const int sr8 = lane >> 3;
  const int sx8 = ((lane & 7) ^ sr8) * 8;
  const int wq = __builtin_amdgcn_readfirstlane(w);
  const unsigned short* aSrc = Asel + (size_t)(m0 + wq * 32 + sr8) * DD + sx8;
  // B fragment base: row n0+wn*64+fr, col hi*8; frag(nf,ks)@kt adds
  // nf*16*DD + kt*64 + ks*32
  const unsigned short* bBase = Bt + (size_t)(n0 + wn * 64 + fr) * DD + hi * 8;

#define GLOAD(SRC, DST)                                                        \
  __builtin_amdgcn_global_load_lds(                                           \
      (const __attribute__((address_space(1))) unsigned int*)(SRC),           \
      (__attribute__((address_space(3))) unsigned int*)(DST), 16, 0, 0)

  // A staging: 4 DMA issues per thread per K-tile
#define STAGEA(T) do {                                                         \
    char* da_ = smem + ((T) & 1) * 16384;                                      \
    const unsigned short* as_ = aSrc + (T) * 64;                               \
    _Pragma("unroll")                                                          \
    for (int i_ = 0; i_ < 4; ++i_)                                             \
      GLOAD(as_ + (size_t)i_ * 8 * DD, da_ + (wq * 32 + i_ * 8) * 128);        \
  } while (0)

  // B fragments: 8 x 16B register loads per thread per K-tile
#define LOADB(REG, T) do {                                                     \
    _Pragma("unroll")                                                          \
    for (int nf_ = 0; nf_ < 4; ++nf_) {                                        \
      (REG)[nf_ * 2 + 0] = *(const bf16x8*)(bBase + (size_t)nf_ * 16 * DD + (T) * 64);      \
      (REG)[nf_ * 2 + 1] = *(const bf16x8*)(bBase + (size_t)nf_ * 16 * DD + (T) * 64 + 32); \
    }                                                                          \
  } while (0)

#define SBO() __builtin_amdgcn_sched_barrier(0)

#define MFMAH(AF, BR, KS)                                                      \
  do {                                                                         \
    __builtin_amdgcn_s_setprio(1);                                             \
    _Pragma("unroll")                                                          \
    for (int mf_ = 0; mf_ < 4; ++mf_)                                          \
      _Pragma("unroll")                                                        \
      for (int nf_ = 0; nf_ < 4; ++nf_)                                        \
        acc[mf_][nf_] = __builtin_amdgcn_mfma_f32_16x16x32_bf16(               \
            (AF)[mf_], (BR)[nf_ * 2 + (KS)], acc[mf_][nf_], 0, 0, 0);          \
    __builtin_amdgcn_s_setprio(0);                                             \
  } while (0)

  const int cb0 = (hi * 16) ^ ((fr & 7) << 4);
  const int cb1 = (64 + hi * 16) ^ ((fr & 7) << 4);
  const int ar = (wm * 64 + fr) * 128;   // + f*2048

  bf16x8 bRA[8], bRB[8];

  // prologue issue order: [B0(8), A0(4), A1(4), B1(8)] = 24 outstanding
  LOADB(bRA, 0);
  STAGEA(0);
  STAGEA(1);
  LOADB(bRB, 1);

  // per-iter body; BREG selection is compile-time (full unroll)
#define ITER_BODY(KT, BREG)                                                    \
  do {                                                                         \
    const char* pA_ = smem + ((KT) & 1) * 16384;                               \
    bf16x8 a0[4], a1[4];                                                       \
    _Pragma("unroll")                                                          \
    for (int f_ = 0; f_ < 4; ++f_) a0[f_] = *(const bf16x8*)(pA_ + ar + f_ * 2048 + cb0); \
    _Pragma("unroll")                                                          \
    for (int f_ = 0; f_ < 4; ++f_) a1[f_] = *(const bf16x8*)(pA_ + ar + f_ * 2048 + cb1); \
    asm volatile("s_waitcnt lgkmcnt(4)" ::: "memory");                          \
    SBO();                                                                     \
    MFMAH(a0, BREG, 0);                                                        \
    asm volatile("s_waitcnt lgkmcnt(0)" ::: "memory");                          \
    SBO();                                                                     \
    __builtin_amdgcn_s_barrier();   /* all waves done reading A buf KT */      \
    SBO();                                                                     \
    if ((KT) < 10) STAGEA((KT) + 2);                                           \
    SBO();                                                                     \
    MFMAH(a1, BREG, 1);                                                        \
    if ((KT) < 10) LOADB(BREG, (KT) + 2);  /* after last use of BREG */        \
  } while (0)

#pragma unroll
  for (int kt = 0; kt < NT; ++kt) {
    // head wait: A(kt) landed in LDS, B(kt) landed in regs
    if (kt < NT - 1) {
      asm volatile("s_waitcnt vmcnt(12)" ::: "memory");
    } else {
      asm volatile("s_waitcnt vmcnt(0)" ::: "memory");
    }
    SBO();
    __builtin_amdgcn_s_barrier();   // publish A(kt) to all waves
    SBO();
    if ((kt & 1) == 0) {
      ITER_BODY(kt, bRA);
    } else {
      ITER_BODY(kt, bRB);
    }
  }
#undef ITER_BODY
#undef MFMAH
#undef SBO
#undef LOADB
#undef STAGEA
#undef GLOAD

  // ---------------- fused epilogues
  if (isQ) {
#pragma unroll
    for (int mf = 0; mf < 4; ++mf) {
      const int r0 = m0 + wm * 64 + mf * 16 + hi * 4;
      const uchar4 nm = *(const uchar4*)&nmask[r0];
      const float g0 = nm.x ? 1.f : 0.f;
      const float g1 = nm.y ? 1.f : 0.f;
      const float g2 = nm.z ? 1.f : 0.f;
      const float g3 = nm.w ? 1.f : 0.f;
#pragma unroll
      for (int nf = 0; nf < 4; ++nf) {
        const int gnc = n0 + wn * 64 + nf * 16 + fr;
        const float bvs = bias[gnc];
        const f32x4 a = acc[mf][nf];
        qp[(size_t)(r0 + 0) * 768 + gnc] = f2bf((a[0] + bvs) * g0);
        qp[(size_t)(r0 + 1) * 768 + gnc] = f2bf((a[1] + bvs) * g1);
        qp[(size_t)(r0 + 2) * 768 + gnc] = f2bf((a[2] + bvs) * g2);
        qp[(size_t)(r0 + 3) * 768 + gnc] = f2bf((a[3] + bvs) * g3);
      }
    }
  } else if (n0 < 1536) {
#pragma unroll
    for (int nf = 0; nf < 4; ++nf) {
      const int nc = wn * 64 + nf * 16 + fr;
      const float bvs = bias[n0 + nc];
      const int gnc = n0 - 768 + nc;
#pragma unroll
      for (int mf = 0; mf < 4; ++mf) {
        const int gmr = m0 + wm * 64 + mf * 16 + hi * 4;
#pragma unroll
        for (int j = 0; j < 4; ++j)
          Kbuf[(size_t)(gmr + j) * 768 + gnc] = f2bf(acc[mf][nf][j] + bvs);
      }
    }
  } else {
    const int b = m0 >> 9;
    const int s0 = m0 & 511;
    unsigned short* lt = (unsigned short*)smem;   // [128 n][136 m] = 34816 B
#pragma unroll
    for (int nf = 0; nf < 4; ++nf) {
      const int nl = wn * 64 + nf * 16 + fr;
      const float bvs = bias[n0 + nl];
#pragma unroll
      for (int mf = 0; mf < 4; ++mf) {
        const int mb = wm * 64 + mf * 16 + hi * 4;
        ushort4 pk;
        pk.x = f2bf(acc[mf][nf][0] + bvs);
        pk.y = f2bf(acc[mf][nf][1] + bvs);
        pk.z = f2bf(acc[mf][nf][2] + bvs);
        pk.w = f2bf(acc[mf][nf][3] + bvs);
        *(ushort4*)&lt[nl * 136 + mb] = pk;
      }
    }
    __syncthreads();
#pragma unroll
    for (int i = 0; i < 8; ++i) {
      const int row = i * 16 + (t >> 4);
      const int ch = t & 15;
      const u16x8 v = *(const u16x8*)&lt[row * 136 + ch * 8];
      const int n = n0 - 1536 + row;
      const int h2 = n >> 6, d2 = n & 63;
      *(u16x8*)(vT + ((size_t)((b * HH + h2) * HDIM + d2)) * 512 + s0 + ch * 8) = v;
    }
  }
}

// ---------------------------------------------------------------- attention
// slopes pre-scaled by log2(e)
__constant__ float c_slopes2[12] = {
    0.72134752f, 0.36067376f, 0.18033688f, 0.09016844f,
    0.04508422f, 0.02254211f, 0.011271055f, 0.0056355275f,
    1.02013945f, 0.51006972f, 0.25503486f, 0.12751743f};

// 8-wave block; block covers HALF the q-rows of one (b,h): wave w owns
// 16 q-rows (1 m-frag). 768 blocks x 8 waves, 4 waves/SIMD.
__global__ __launch_bounds__(512, 4) void attn_mfma(
    const unsigned short* __restrict__ qp,    // [B][OL][768] bf16
    const unsigned short* __restrict__ Kb,    // [B*S][768] bf16
    const unsigned short* __restrict__ vT,    // [B][H][64][512] bf16
    const float* __restrict__ kbias,          // [B][S], pre-scaled log2e
    const unsigned char* __restrict__ nmask,  // [B][OL]
    float* __restrict__ out) {                // [B][OL][768]
  __shared__ __align__(16) char smem[51200];
  const int t = threadIdx.x;
  const int lane = t & 63;
  const int w = t >> 6;
  const int wq = __builtin_amdgcn_readfirstlane(w);
  const int fr = lane & 15, hi = lane >> 4;

  const int p = blockIdx.x;
  const int l = (p & 7) * 96 + (p >> 3);
  const int qb = l & 1;
  const int bh = l >> 1;
  const int h = bh % HH, b = bh / HH;
  const int q0 = qb * 128 + wq * 16;    // this wave's 16 q-rows

  char* ptb = smem + 32768 + wq * 2048;
  float* kbl = (float*)(smem + 49152);

  const int srow = lane >> 3;
  const int scol = ((lane & 7) ^ srow) * 8;

#define GLOAD(SRC, DST)                                                        \
  __builtin_amdgcn_global_load_lds(                                           \
      (const __attribute__((address_space(1))) unsigned int*)(SRC),           \
      (__attribute__((address_space(3))) unsigned int*)(DST), 16, 0, 0)

  if (wq == 0) {
    GLOAD(kbias + b * SS + lane * 4, smem + 49152);
    GLOAD(kbias + b * SS + 256 + lane * 4, smem + 50176);
  }

  bf16x8 qf[2];
#pragma unroll
  for (int ks = 0; ks < 2; ++ks)
    qf[ks] = *(const bf16x8*)(qp + (size_t)(b * OL + q0 + fr) * DD +
                              h * HDIM + ks * 32 + hi * 8);

  int nmv = (int)nmask[b * OL + q0 + (lane & 15)];
  int qmbits = 0;
#pragma unroll
  for (int j = 0; j < 4; ++j)
    if (__shfl(nmv, hi * 4 + j, 64)) qmbits |= 1 << j;

  const float slope2 = c_slopes2[h];
  f32x4 oacc[4] = {};
  float lpart[4] = {};

#define STAGE(TILE, BUF) do {                                                  \
    char* kd_ = smem + (BUF) * 8192 + wq * 1024;                               \
    char* vd_ = smem + 16384 + (BUF) * 8192 + wq * 1024;                       \
    const unsigned short* ks_ =                                                \
        Kb + (size_t)(b * SS + (TILE) * 64 + wq * 8 + srow) * 768 + h * HDIM + scol; \
    const unsigned short* vs_ =                                                \
        vT + (size_t)((b * HH + h) * HDIM + wq * 8 + srow) * SS + (TILE) * 64 + scol; \
    GLOAD(ks_, kd_);                                                           \
    GLOAD(vs_, vd_);                                                           \
  } while (0)

  __builtin_amdgcn_sched_barrier(0);
  STAGE(0, 0);
  STAGE(1, 1);
  __builtin_amdgcn_sched_barrier(0);

  for (int tile = 0; tile < 8; ++tile) {
    const int cur = tile & 1;
    const int key0 = tile * 64;
    if (tile < 7) {
      asm volatile("s_waitcnt vmcnt(2)" ::: "memory");
    } else {
      asm volatile("s_waitcnt vmcnt(0)" ::: "memory");
    }
    __builtin_amdgcn_sched_barrier(0);
    __builtin_amdgcn_s_barrier();
    __builtin_amdgcn_sched_barrier(0);

    char* ktb = smem + cur * 8192;
    char* vtb = smem + 16384 + cur * 8192;

    // ---- QK^T (1 m-frag x 4 n-frags x 2 ks)
    f32x4 sacc[4] = {};
#pragma unroll
    for (int ks = 0; ks < 2; ++ks) {
      bf16x8 kf[4];
#pragma unroll
      for (int n = 0; n < 4; ++n) {
        const int by = ((n * 16 + fr) * 128 + (ks * 64 + hi * 16)) ^ ((fr & 7) << 4);
        kf[n] = *(const bf16x8*)(ktb + by);
      }
#pragma unroll
      for (int n = 0; n < 4; ++n)
        sacc[n] = __builtin_amdgcn_mfma_f32_16x16x32_bf16(qf[ks], kf[n], sacc[n], 0, 0, 0);
    }

    // ---- fixed-max log2-domain softmax; P -> LDS (bf16)
    float kbv[4], keyfv[4];
#pragma unroll
    for (int n = 0; n < 4; ++n) {
      kbv[n] = kbl[key0 + n * 16 + fr];
      keyfv[n] = (float)(key0 + n * 16 + fr);
    }
#pragma unroll
    for (int j = 0; j < 4; ++j) {
      const bool qm = (qmbits >> j) & 1;
      const float qvf = (float)(q0 + hi * 4 + j);
      float lp = lpart[j];
#pragma unroll
      for (int n = 0; n < 4; ++n) {
        const float biasv = qm ? kbv[n] : 0.f;
        const float rel = fabsf(keyfv[n] - qvf);
        float tv = fmaf(sacc[n][j], 0.18033688011f, biasv);
        tv = fmaf(rel, -slope2, tv);
        float pe;
        asm("v_exp_f32 %0, %1" : "=v"(pe) : "v"(tv));
        lp += pe;
        const int by = ((hi * 4 + j) * 128 + (n * 16 + fr) * 2) ^
                       (((hi * 4 + j) & 7) << 4);
        *(unsigned short*)(ptb + by) = f2bf(pe);
      }
      lpart[j] = lp;
    }
    asm volatile("s_waitcnt lgkmcnt(0)" ::: "memory");
    __builtin_amdgcn_sched_barrier(0);

    // ---- PV
#pragma unroll
    for (int ks = 0; ks < 2; ++ks) {
      bf16x8 pf, vf[4];
      {
        const int by = (fr * 128 + (ks * 64 + hi * 16)) ^ ((fr & 7) << 4);
        pf = *(const bf16x8*)(ptb + by);
      }
#pragma unroll
      for (int nd = 0; nd < 4; ++nd) {
        const int by = ((nd * 16 + fr) * 128 + (ks * 64 + hi * 16)) ^ ((fr & 7) << 4);
        vf[nd] = *(const bf16x8*)(vtb + by);
      }
#pragma unroll
      for (int nd = 0; nd < 4; ++nd)
        oacc[nd] = __builtin_amdgcn_mfma_f32_16x16x32_bf16(pf, vf[nd], oacc[nd], 0, 0, 0);
    }

    __builtin_amdgcn_sched_barrier(0);
    __builtin_amdgcn_s_barrier();
    __builtin_amdgcn_sched_barrier(0);
    if (tile + 2 < 8) STAGE(tile + 2, cur);
  }
#undef STAGE
#undef GLOAD

  // ---- epilogue: reduce l, normalize, transpose via per-wave LDS tile
  float* ot = (float*)(smem + wq * 4352);   // 16 x 68 f32
#pragma unroll
  for (int j = 0; j < 4; ++j) {
    float lv = lpart[j];
    lv += __shfl_xor(lv, 1, 64);
    lv += __shfl_xor(lv, 2, 64);
    lv += __shfl_xor(lv, 4, 64);
    lv += __shfl_xor(lv, 8, 64);
    const float rl = 1.f / lv;
    const int row = hi * 4 + j;
#pragma unroll
    for (int nd = 0; nd < 4; ++nd)
      ot[row * 68 + nd * 16 + fr] = oacc[nd][j] * rl;
  }
  asm volatile("s_waitcnt lgkmcnt(0)" ::: "memory");
  __builtin_amdgcn_sched_barrier(0);
#pragma unroll
  for (int i = 0; i < 4; ++i) {
    const int idx = i * 64 + lane;       // float4 index, 256 per wave
    const int row = idx >> 4, c4 = idx & 15;
    const float4 v = *(const float4*)&ot[row * 68 + c4 * 4];
    *(float4*)(out + (size_t)(b * OL + q0 + row) * DD + h * HDIM + c4 * 4) = v;
  }
}

// ---------------------------------------------------------------- launch
extern "C" void kernel_launch(void* const* d_in, const int* in_sizes, int n_in,
                              void* d_out, int out_size, void* d_ws, size_t ws_size,
                              hipStream_t stream) {
  const float* hidden = (const float*)d_in[0];
  const void* maskraw = d_in[1];
  const float* W = (const float*)d_in[2];
  const float* bias = (const float*)d_in[3];
  float* out = (float*)d_out;

  char* ws = (char*)d_ws;
  unsigned short* Abf   = (unsigned short*)(ws);                 // 25,165,824 B
  unsigned short* Btb   = (unsigned short*)(ws + 25165824);      //  3,538,944 B
  unsigned short* Kbuf  = (unsigned short*)(ws + 28704768);      // 25,165,824 B
  unsigned short* vT    = (unsigned short*)(ws + 53870592);      // 25,165,824 B
  unsigned short* qp    = (unsigned short*)(ws + 79036416);      // 12,582,912 B
  float* kbias          = (float*)(ws + 91619328);               //     65,536 B
  float* invn           = (float*)(ws + 91684864);               //     32,768 B
  unsigned char* nmask  = (unsigned char*)(ws + 91717632);       //      8,192 B
  unsigned short* Apool = (unsigned short*)(ws + 91725824);      // 12,582,912 B

  float* out_nm = out + (size_t)BB * OL * DD;  // new_mask part of d_out

  prep_all<<<7936, 256, 0, stream>>>(hidden, maskraw, W, Btb, Abf, Apool,
                                     kbias, invn, nmask, out_nm);
  gemm_qkv<<<1920, 256, 0, stream>>>(Abf, Apool, Btb, bias, Kbuf, qp, vT, nmask);
  attn_mfma<<<768, 512, 0, stream>>>(qp, Kbuf, vT, kbias, nmask, out);
}

// Round 18
// 96.624 us; speedup vs baseline: 1.6044x; 1.6044x over previous
//
#include <hip/hip_runtime.h>

// Problem constants
#define BB 32
#define SS 512
#define DD 768
#define HH 12
#define HDIM 64
#define OL 256        // pooled query length
#define NQKV 2304     // 3*DD
#define GM (BB*SS)    // 16384 rows into the QKV GEMM

#define NEG2 (-14426.9504089f)   // -10000 * log2(e)

typedef __bf16 bf16_t;
typedef bf16_t bf16x8 __attribute__((ext_vector_type(8)));
typedef float f32x4 __attribute__((ext_vector_type(4)));
typedef unsigned short u16x8 __attribute__((ext_vector_type(8)));

__device__ __forceinline__ unsigned short f2bf(float f) {
  unsigned u = __float_as_uint(f);
  u = u + 0x7FFFu + ((u >> 16) & 1u);   // RNE
  return (unsigned short)(u >> 16);
}
__device__ __forceinline__ float b2f(unsigned short s) {
  return __uint_as_float(((unsigned)s) << 16);
}

// ---------------------------------------------------------------- fused prep
// blocks [0,1728): W f32->bf16
// blocks [1728,1792): mask -> kbias/invn/nmask/out_nm
// blocks [1792,7936): hidden -> Abf (bf16) + Apool (mask-weighted pooled bf16)
__global__ __launch_bounds__(256) void prep_all(
    const float* __restrict__ hidden,
    const void* __restrict__ mraw,
    const float* __restrict__ W,
    unsigned short* __restrict__ Btb,
    unsigned short* __restrict__ Abf,
    unsigned short* __restrict__ Apool,
    float* __restrict__ kbias,
    float* __restrict__ invn,
    unsigned char* __restrict__ nmask,
    float* __restrict__ out_nm) {
  const int blk = blockIdx.x;
  const int t = threadIdx.x;
  const unsigned char* mb = (const unsigned char*)mraw;

  if (blk < 1728) {
    // ---- W conversion (442368 float4 items)
    const int i = blk * 256 + t;
    float4 v = ((const float4*)W)[i];
    ushort4 o;
    o.x = f2bf(v.x); o.y = f2bf(v.y); o.z = f2bf(v.z); o.w = f2bf(v.w);
    ((ushort4*)Btb)[i] = o;
  } else if (blk < 1792) {
    // ---- mask prep (16384 positions)
    const int idx = (blk - 1728) * 256 + t;
    const int b = idx >> 9, s = idx & 511;
    const bool isbyte = (mb[1] != 0);
    const int mv = isbyte ? (int)(mb[idx] != 0) : (int)(((const int*)mraw)[idx] != 0);
    kbias[idx] = mv ? 0.f : NEG2;
    if (s < OL) {
      const int i0 = b * SS + 2 * s, i1 = i0 + 1;
      const int m0 = isbyte ? (int)(mb[i0] != 0) : (int)(((const int*)mraw)[i0] != 0);
      const int m1 = isbyte ? (int)(mb[i1] != 0) : (int)(((const int*)mraw)[i1] != 0);
      const int n = m0 + m1;
      invn[b * OL + s] = (n > 0) ? 1.f / (float)n : 1.f;
      nmask[b * OL + s] = (n > 0) ? 1 : 0;
      out_nm[b * OL + s] = (n > 0) ? 1.f : 0.f;
    }
  } else {
    // ---- hidden conversion + pooling (1572864 items; reads mask directly)
    const int i = (blk - 1792) * 256 + t;
    const int c = (i % 192) * 4;
    const int ol = i / 192;
    const int b = ol >> 8, o = ol & 255;
    const int s0 = b * SS + 2 * o;
    const bool isbyte = (mb[1] != 0);
    const int m0 = isbyte ? (int)(mb[s0] != 0) : (int)(((const int*)mraw)[s0] != 0);
    const int m1 = isbyte ? (int)(mb[s0 + 1] != 0) : (int)(((const int*)mraw)[s0 + 1] != 0);
    const int n = m0 + m1;
    const float inv = (n > 0) ? 1.f / (float)n : 1.f;
    const float m0v = (float)m0, m1v = (float)m1;
    const float4 h0 = *(const float4*)(hidden + (size_t)s0 * DD + c);
    const float4 h1 = *(const float4*)(hidden + (size_t)(s0 + 1) * DD + c);
    ushort4 a0, a1, ap;
    a0.x = f2bf(h0.x); a0.y = f2bf(h0.y); a0.z = f2bf(h0.z); a0.w = f2bf(h0.w);
    a1.x = f2bf(h1.x); a1.y = f2bf(h1.y); a1.z = f2bf(h1.z); a1.w = f2bf(h1.w);
    ap.x = f2bf((h0.x * m0v + h1.x * m1v) * inv);
    ap.y = f2bf((h0.y * m0v + h1.y * m1v) * inv);
    ap.z = f2bf((h0.z * m0v + h1.z * m1v) * inv);
    ap.w = f2bf((h0.w * m0v + h1.w * m1v) * inv);
    *(ushort4*)(Abf + (size_t)s0 * DD + c) = a0;
    *(ushort4*)(Abf + (size_t)(s0 + 1) * DD + c) = a1;
    *(ushort4*)(Apool + (size_t)ol * DD + c) = ap;
  }
}

// ---------------------------------------------------------------- QKV GEMM
// R8-proven structure: 128x128 tile, BK=64, 4 waves (2M x 2N), dbuf 64 KiB
// -> 2 blocks/CU, counted vmcnt(8), T2 XOR-swizzle, T5 setprio.
// Grid 1920 = 8 XCDs x 240: l<1536 -> K/V over full M=16384 (n0=768+...);
// l>=1536 -> Q over POOLED M=8192 (A=Apool, n0=0..767).
#define NT 12   // 768 / 64
__global__ __launch_bounds__(256, 2) void gemm_qkv(
    const unsigned short* __restrict__ A,      // [16384][768]
    const unsigned short* __restrict__ Apool,  // [8192][768]
    const unsigned short* __restrict__ Bt,     // [2304][768]
    const float* __restrict__ bias,
    unsigned short* __restrict__ Kbuf,   // [B*S][768]
    unsigned short* __restrict__ qp,     // [B*OL][768]
    unsigned short* __restrict__ vT,     // [B][H][64][512]
    const unsigned char* __restrict__ nmask) {
  __shared__ __align__(16) char smem[65536];  // 2 x (A 16K + B 16K)

  const int t = threadIdx.x;
  const int lane = t & 63;
  const int w = t >> 6;          // 0..3
  const int wm = w >> 1, wn = w & 1;
  const int fr = lane & 15, hi = lane >> 4;

  const int p = blockIdx.x;
  const int l = (p & 7) * 240 + (p >> 3);
  const bool isQ = l >= 1536;
  int m0, n0;
  if (!isQ) { m0 = (l / 12) * 128; n0 = 768 + (l % 12) * 128; }
  else      { const int l2 = l - 1536; m0 = (l2 / 6) * 128; n0 = (l2 % 6) * 128; }
  const unsigned short* Asel = isQ ? Apool : A;

  f32x4 acc[4][4] = {};

  const int sr8 = lane >> 3;
  const int sx8 = ((lane & 7) ^ sr8) * 8;
  const int wq = __builtin_amdgcn_readfirstlane(w);
  const unsigned short* aSrc = Asel + (size_t)(m0 + wq * 32 + sr8) * DD + sx8;
  const unsigned short* bSrc = Bt + (size_t)(n0 + wq * 32 + sr8) * DD + sx8;

#define GLOAD(SRC, DST)                                                        \
  __builtin_amdgcn_global_load_lds(                                           \
      (const __attribute__((address_space(1))) unsigned int*)(SRC),           \
      (__attribute__((address_space(3))) unsigned int*)(DST), 16, 0, 0)

#define STAGE(T) do {                                                          \
    char* da_ = smem + ((T) & 1) * 32768;                                      \
    char* db_ = da_ + 16384;                                                   \
    const unsigned short* as_ = aSrc + (T) * 64;                               \
    const unsigned short* bs_ = bSrc + (T) * 64;                               \
    _Pragma("unroll")                                                          \
    for (int i_ = 0; i_ < 4; ++i_) {                                           \
      GLOAD(as_ + (size_t)i_ * 8 * DD, da_ + (wq * 32 + i_ * 8) * 128);        \
      GLOAD(bs_ + (size_t)i_ * 8 * DD, db_ + (wq * 32 + i_ * 8) * 128);        \
    }                                                                          \
  } while (0)

  STAGE(0);
  STAGE(1);

  const int cb0 = (hi * 16) ^ ((fr & 7) << 4);
  const int cb1 = (64 + hi * 16) ^ ((fr & 7) << 4);

  for (int kt = 0; kt < NT; ++kt) {
    if (kt < NT - 1) {
      asm volatile("s_waitcnt vmcnt(8)" ::: "memory");
    } else {
      asm volatile("s_waitcnt vmcnt(0)" ::: "memory");
    }
    __builtin_amdgcn_sched_barrier(0);
    __builtin_amdgcn_s_barrier();
    __builtin_amdgcn_sched_barrier(0);

    const char* bA = smem + (kt & 1) * 32768;
    const char* bB = bA + 16384;

    bf16x8 a0[4], b0[4], a1[4], b1[4];
#pragma unroll
    for (int f = 0; f < 4; ++f) {
      a0[f] = *(const bf16x8*)(bA + (wm * 64 + f * 16 + fr) * 128 + cb0);
      b0[f] = *(const bf16x8*)(bB + (wn * 64 + f * 16 + fr) * 128 + cb0);
    }
    __builtin_amdgcn_sched_barrier(0);
#pragma unroll
    for (int f = 0; f < 4; ++f) {
      a1[f] = *(const bf16x8*)(bA + (wm * 64 + f * 16 + fr) * 128 + cb1);
      b1[f] = *(const bf16x8*)(bB + (wn * 64 + f * 16 + fr) * 128 + cb1);
    }
    asm volatile("s_waitcnt lgkmcnt(8)" ::: "memory");
    __builtin_amdgcn_sched_barrier(0);
    __builtin_amdgcn_s_setprio(1);
#pragma unroll
    for (int mf = 0; mf < 4; ++mf)
#pragma unroll
      for (int nf = 0; nf < 4; ++nf)
        acc[mf][nf] = __builtin_amdgcn_mfma_f32_16x16x32_bf16(
            a0[mf], b0[nf], acc[mf][nf], 0, 0, 0);
    __builtin_amdgcn_s_setprio(0);
    asm volatile("s_waitcnt lgkmcnt(0)" ::: "memory");
    __builtin_amdgcn_sched_barrier(0);
    __builtin_amdgcn_s_barrier();
    __builtin_amdgcn_sched_barrier(0);
    if (kt + 2 < NT) STAGE(kt + 2);
    __builtin_amdgcn_sched_barrier(0);
    __builtin_amdgcn_s_setprio(1);
#pragma unroll
    for (int mf = 0; mf < 4; ++mf)
#pragma unroll
      for (int nf = 0; nf < 4; ++nf)
        acc[mf][nf] = __builtin_amdgcn_mfma_f32_16x16x32_bf16(
            a1[mf], b1[nf], acc[mf][nf], 0, 0, 0);
    __builtin_amdgcn_s_setprio(0);
  }
#undef STAGE
#undef GLOAD

  // ---------------- fused epilogues
  if (isQ) {
#pragma unroll
    for (int mf = 0; mf < 4; ++mf) {
      const int r0 = m0 + wm * 64 + mf * 16 + hi * 4;
      const uchar4 nm = *(const uchar4*)&nmask[r0];
      const float g0 = nm.x ? 1.f : 0.f;
      const float g1 = nm.y ? 1.f : 0.f;
      const float g2 = nm.z ? 1.f : 0.f;
      const float g3 = nm.w ? 1.f : 0.f;
#pragma unroll
      for (int nf = 0; nf < 4; ++nf) {
        const int gnc = n0 + wn * 64 + nf * 16 + fr;
        const float bvs = bias[gnc];
        const f32x4 a = acc[mf][nf];
        qp[(size_t)(r0 + 0) * 768 + gnc] = f2bf((a[0] + bvs) * g0);
        qp[(size_t)(r0 + 1) * 768 + gnc] = f2bf((a[1] + bvs) * g1);
        qp[(size_t)(r0 + 2) * 768 + gnc] = f2bf((a[2] + bvs) * g2);
        qp[(size_t)(r0 + 3) * 768 + gnc] = f2bf((a[3] + bvs) * g3);
      }
    }
  } else if (n0 < 1536) {
#pragma unroll
    for (int nf = 0; nf < 4; ++nf) {
      const int nc = wn * 64 + nf * 16 + fr;
      const float bvs = bias[n0 + nc];
      const int gnc = n0 - 768 + nc;
#pragma unroll
      for (int mf = 0; mf < 4; ++mf) {
        const int gmr = m0 + wm * 64 + mf * 16 + hi * 4;
#pragma unroll
        for (int j = 0; j < 4; ++j)
          Kbuf[(size_t)(gmr + j) * 768 + gnc] = f2bf(acc[mf][nf][j] + bvs);
      }
    }
  } else {
    const int b = m0 >> 9;
    const int s0 = m0 & 511;
    unsigned short* lt = (unsigned short*)smem;
#pragma unroll
    for (int nf = 0; nf < 4; ++nf) {
      const int nl = wn * 64 + nf * 16 + fr;
      const float bvs = bias[n0 + nl];
#pragma unroll
      for (int mf = 0; mf < 4; ++mf) {
        const int mb = wm * 64 + mf * 16 + hi * 4;
        ushort4 pk;
        pk.x = f2bf(acc[mf][nf][0] + bvs);
        pk.y = f2bf(acc[mf][nf][1] + bvs);
        pk.z = f2bf(acc[mf][nf][2] + bvs);
        pk.w = f2bf(acc[mf][nf][3] + bvs);
        *(ushort4*)&lt[nl * 136 + mb] = pk;
      }
    }
    __syncthreads();
#pragma unroll
    for (int i = 0; i < 8; ++i) {
      const int row = i * 16 + (t >> 4);
      const int ch = t & 15;
      const u16x8 v = *(const u16x8*)&lt[row * 136 + ch * 8];
      const int n = n0 - 1536 + row;
      const int h2 = n >> 6, d2 = n & 63;
      *(u16x8*)(vT + ((size_t)((b * HH + h2) * HDIM + d2)) * 512 + s0 + ch * 8) = v;
    }
  }
}

// ---------------------------------------------------------------- attention
// slopes pre-scaled by log2(e)
__constant__ float c_slopes2[12] = {
    0.72134752f, 0.36067376f, 0.18033688f, 0.09016844f,
    0.04508422f, 0.02254211f, 0.011271055f, 0.0056355275f,
    1.02013945f, 0.51006972f, 0.25503486f, 0.12751743f};

// 8-wave block; block covers HALF the q-rows of one (b,h): wave w owns
// 16 q-rows (1 m-frag). 768 blocks x 8 waves, 4 waves/SIMD.
__global__ __launch_bounds__(512, 4) void attn_mfma(
    const unsigned short* __restrict__ qp,    // [B][OL][768] bf16
    const unsigned short* __restrict__ Kb,    // [B*S][768] bf16
    const unsigned short* __restrict__ vT,    // [B][H][64][512] bf16
    const float* __restrict__ kbias,          // [B][S], pre-scaled log2e
    const unsigned char* __restrict__ nmask,  // [B][OL]
    float* __restrict__ out) {                // [B][OL][768]
  __shared__ __align__(16) char smem[51200];
  const int t = threadIdx.x;
  const int lane = t & 63;
  const int w = t >> 6;
  const int wq = __builtin_amdgcn_readfirstlane(w);
  const int fr = lane & 15, hi = lane >> 4;

  const int p = blockIdx.x;
  const int l = (p & 7) * 96 + (p >> 3);
  const int qb = l & 1;
  const int bh = l >> 1;
  const int h = bh % HH, b = bh / HH;
  const int q0 = qb * 128 + wq * 16;    // this wave's 16 q-rows

  char* ptb = smem + 32768 + wq * 2048;
  float* kbl = (float*)(smem + 49152);

  const int srow = lane >> 3;
  const int scol = ((lane & 7) ^ srow) * 8;

#define GLOAD(SRC, DST)                                                        \
  __builtin_amdgcn_global_load_lds(                                           \
      (const __attribute__((address_space(1))) unsigned int*)(SRC),           \
      (__attribute__((address_space(3))) unsigned int*)(DST), 16, 0, 0)

  if (wq == 0) {
    GLOAD(kbias + b * SS + lane * 4, smem + 49152);
    GLOAD(kbias + b * SS + 256 + lane * 4, smem + 50176);
  }

  bf16x8 qf[2];
#pragma unroll
  for (int ks = 0; ks < 2; ++ks)
    qf[ks] = *(const bf16x8*)(qp + (size_t)(b * OL + q0 + fr) * DD +
                              h * HDIM + ks * 32 + hi * 8);

  int nmv = (int)nmask[b * OL + q0 + (lane & 15)];
  int qmbits = 0;
#pragma unroll
  for (int j = 0; j < 4; ++j)
    if (__shfl(nmv, hi * 4 + j, 64)) qmbits |= 1 << j;

  const float slope2 = c_slopes2[h];
  f32x4 oacc[4] = {};
  float lpart[4] = {};

#define STAGE(TILE, BUF) do {                                                  \
    char* kd_ = smem + (BUF) * 8192 + wq * 1024;                               \
    char* vd_ = smem + 16384 + (BUF) * 8192 + wq * 1024;                       \
    const unsigned short* ks_ =                                                \
        Kb + (size_t)(b * SS + (TILE) * 64 + wq * 8 + srow) * 768 + h * HDIM + scol; \
    const unsigned short* vs_ =                                                \
        vT + (size_t)((b * HH + h) * HDIM + wq * 8 + srow) * SS + (TILE) * 64 + scol; \
    GLOAD(ks_, kd_);                                                           \
    GLOAD(vs_, vd_);                                                           \
  } while (0)

  __builtin_amdgcn_sched_barrier(0);
  STAGE(0, 0);
  STAGE(1, 1);
  __builtin_amdgcn_sched_barrier(0);

  for (int tile = 0; tile < 8; ++tile) {
    const int cur = tile & 1;
    const int key0 = tile * 64;
    if (tile < 7) {
      asm volatile("s_waitcnt vmcnt(2)" ::: "memory");
    } else {
      asm volatile("s_waitcnt vmcnt(0)" ::: "memory");
    }
    __builtin_amdgcn_sched_barrier(0);
    __builtin_amdgcn_s_barrier();
    __builtin_amdgcn_sched_barrier(0);

    char* ktb = smem + cur * 8192;
    char* vtb = smem + 16384 + cur * 8192;

    // ---- QK^T (1 m-frag x 4 n-frags x 2 ks)
    f32x4 sacc[4] = {};
#pragma unroll
    for (int ks = 0; ks < 2; ++ks) {
      bf16x8 kf[4];
#pragma unroll
      for (int n = 0; n < 4; ++n) {
        const int by = ((n * 16 + fr) * 128 + (ks * 64 + hi * 16)) ^ ((fr & 7) << 4);
        kf[n] = *(const bf16x8*)(ktb + by);
      }
#pragma unroll
      for (int n = 0; n < 4; ++n)
        sacc[n] = __builtin_amdgcn_mfma_f32_16x16x32_bf16(qf[ks], kf[n], sacc[n], 0, 0, 0);
    }

    // ---- fixed-max log2-domain softmax; P -> LDS (bf16)
    float kbv[4], keyfv[4];
#pragma unroll
    for (int n = 0; n < 4; ++n) {
      kbv[n] = kbl[key0 + n * 16 + fr];
      keyfv[n] = (float)(key0 + n * 16 + fr);
    }
#pragma unroll
    for (int j = 0; j < 4; ++j) {
      const bool qm = (qmbits >> j) & 1;
      const float qvf = (float)(q0 + hi * 4 + j);
      float lp = lpart[j];
#pragma unroll
      for (int n = 0; n < 4; ++n) {
        const float biasv = qm ? kbv[n] : 0.f;
        const float rel = fabsf(keyfv[n] - qvf);
        float tv = fmaf(sacc[n][j], 0.18033688011f, biasv);
        tv = fmaf(rel, -slope2, tv);
        float pe;
        asm("v_exp_f32 %0, %1" : "=v"(pe) : "v"(tv));
        lp += pe;
        const int by = ((hi * 4 + j) * 128 + (n * 16 + fr) * 2) ^
                       (((hi * 4 + j) & 7) << 4);
        *(unsigned short*)(ptb + by) = f2bf(pe);
      }
      lpart[j] = lp;
    }
    asm volatile("s_waitcnt lgkmcnt(0)" ::: "memory");
    __builtin_amdgcn_sched_barrier(0);

    // ---- PV
#pragma unroll
    for (int ks = 0; ks < 2; ++ks) {
      bf16x8 pf, vf[4];
      {
        const int by = (fr * 128 + (ks * 64 + hi * 16)) ^ ((fr & 7) << 4);
        pf = *(const bf16x8*)(ptb + by);
      }
#pragma unroll
      for (int nd = 0; nd < 4; ++nd) {
        const int by = ((nd * 16 + fr) * 128 + (ks * 64 + hi * 16)) ^ ((fr & 7) << 4);
        vf[nd] = *(const bf16x8*)(vtb + by);
      }
#pragma unroll
      for (int nd = 0; nd < 4; ++nd)
        oacc[nd] = __builtin_amdgcn_mfma_f32_16x16x32_bf16(pf, vf[nd], oacc[nd], 0, 0, 0);
    }

    __builtin_amdgcn_sched_barrier(0);
    __builtin_amdgcn_s_barrier();
    __builtin_amdgcn_sched_barrier(0);
    if (tile + 2 < 8) STAGE(tile + 2, cur);
  }
#undef STAGE
#undef GLOAD

  // ---- epilogue: reduce l, normalize, transpose via per-wave LDS tile
  float* ot = (float*)(smem + wq * 4352);   // 16 x 68 f32
#pragma unroll
  for (int j = 0; j < 4; ++j) {
    float lv = lpart[j];
    lv += __shfl_xor(lv, 1, 64);
    lv += __shfl_xor(lv, 2, 64);
    lv += __shfl_xor(lv, 4, 64);
    lv += __shfl_xor(lv, 8, 64);
    const float rl = 1.f / lv;
    const int row = hi * 4 + j;
#pragma unroll
    for (int nd = 0; nd < 4; ++nd)
      ot[row * 68 + nd * 16 + fr] = oacc[nd][j] * rl;
  }
  asm volatile("s_waitcnt lgkmcnt(0)" ::: "memory");
  __builtin_amdgcn_sched_barrier(0);
#pragma unroll
  for (int i = 0; i < 4; ++i) {
    const int idx = i * 64 + lane;       // float4 index, 256 per wave
    const int row = idx >> 4, c4 = idx & 15;
    const float4 v = *(const float4*)&ot[row * 68 + c4 * 4];
    *(float4*)(out + (size_t)(b * OL + q0 + row) * DD + h * HDIM + c4 * 4) = v;
  }
}

// ---------------------------------------------------------------- launch
extern "C" void kernel_launch(void* const* d_in, const int* in_sizes, int n_in,
                              void* d_out, int out_size, void* d_ws, size_t ws_size,
                              hipStream_t stream) {
  const float* hidden = (const float*)d_in[0];
  const void* maskraw = d_in[1];
  const float* W = (const float*)d_in[2];
  const float* bias = (const float*)d_in[3];
  float* out = (float*)d_out;

  char* ws = (char*)d_ws;
  unsigned short* Abf   = (unsigned short*)(ws);                 // 25,165,824 B
  unsigned short* Btb   = (unsigned short*)(ws + 25165824);      //  3,538,944 B
  unsigned short* Kbuf  = (unsigned short*)(ws + 28704768);      // 25,165,824 B
  unsigned short* vT    = (unsigned short*)(ws + 53870592);      // 25,165,824 B
  unsigned short* qp    = (unsigned short*)(ws + 79036416);      // 12,582,912 B
  float* kbias          = (float*)(ws + 91619328);               //     65,536 B
  float* invn           = (float*)(ws + 91684864);               //     32,768 B
  unsigned char* nmask  = (unsigned char*)(ws + 91717632);       //      8,192 B
  unsigned short* Apool = (unsigned short*)(ws + 91725824);      // 12,582,912 B

  float* out_nm = out + (size_t)BB * OL * DD;  // new_mask part of d_out

  prep_all<<<7936, 256, 0, stream>>>(hidden, maskraw, W, Btb, Abf, Apool,
                                     kbias, invn, nmask, out_nm);
  gemm_qkv<<<1920, 256, 0, stream>>>(Abf, Apool, Btb, bias, Kbuf, qp, vT, nmask);
  attn_mfma<<<768, 512, 0, stream>>>(qp, Kbuf, vT, kbias, nmask, out);
}